// Round 9
// baseline (123.487 us; speedup 1.0000x reference)
//
#include <hip/hip_runtime.h>
#include <math.h>

// Problem constants (B,N,C fixed by the reference setup).
#define BB 16
#define NN 2048
#define CC 64
#define TPB 256
#define MAXT 72           // 16-token tiles per batch per side; K,P <= 1152 (+5.6 sigma)
#define IVN (MAXT * 16)
#define E_CONST 2.71828182845904523536f

typedef __attribute__((ext_vector_type(8))) short bf16x8;   // 8 bf16 = 4 VGPR
typedef __attribute__((ext_vector_type(4))) float f32x4;
#define MFMA(A_, B_, C_) __builtin_amdgcn_mfma_f32_16x16x32_bf16(A_, B_, C_, 0, 0, 0)

// round-to-nearest-even f32 -> bf16 bits
__device__ __forceinline__ unsigned short rnbf16(float v) {
    unsigned u = __float_as_uint(v);
    return (unsigned short)((u + 0x7FFFu + ((u >> 16) & 1u)) >> 16);
}
__device__ __forceinline__ float bf2f(unsigned short h) {
    return __uint_as_float((unsigned)h << 16);
}

// ---------------------------------------------------------------------------
// K_pre: zero the A accumulator (d_out) everywhere; blocks 0..BB-1 also run
// ballot-based kept/pruned compaction for batch b and zero S[b,:].
// ---------------------------------------------------------------------------
__global__ __launch_bounds__(TPB) void k_pre(const float* __restrict__ keep,
                                             float* __restrict__ outz,
                                             float* __restrict__ S,
                                             int* __restrict__ cntP,
                                             int* __restrict__ cntK,
                                             int* __restrict__ listP,
                                             int* __restrict__ listK) {
    const int tid = threadIdx.x, lane = tid & 63;

    float4* o4 = (float4*)outz + (size_t)blockIdx.x * 1024;
    float4 z = {0.0f, 0.0f, 0.0f, 0.0f};
#pragma unroll
    for (int i = 0; i < 4; ++i) o4[i * TPB + tid] = z;

    const int b = blockIdx.x;
    if (b >= BB) return;

    __shared__ int cP, cK;
    if (tid == 0) { cP = 0; cK = 0; }
    __syncthreads();
    for (int i = tid; i < NN; i += TPB) S[b * NN + i] = 0.0f;
    const unsigned long long lt = (lane == 63) ? 0x7fffffffffffffffull
                                               : ((1ull << lane) - 1ull);
#pragma unroll
    for (int it = 0; it < NN / TPB; ++it) {
        int n = it * TPB + tid;
        bool kp = keep[b * NN + n] != 0.0f;
        unsigned long long mk = __ballot(kp);
        int nk = __popcll(mk);
        int bk = 0, bp = 0;
        if (lane == 0) {
            bk = atomicAdd(&cK, nk);
            bp = atomicAdd(&cP, 64 - nk);
        }
        bk = __shfl(bk, 0); bp = __shfl(bp, 0);
        int pk = __popcll(mk & lt);
        if (kp) listK[b * NN + bk + pk] = n;
        else    listP[b * NN + bp + (lane - pk)] = n;
    }
    __syncthreads();
    if (tid == 0) { cntP[b] = cP; cntK[b] = cK; }
}

// ---------------------------------------------------------------------------
// K_pack (R24: both operands in ONE launch; packing code byte-identical to
// the R23-verified version). Blocks [0, BB*MAXT) build colA (normalized, no
// ivr); blocks [BB*MAXT, 2*BB*MAXT) build rowB (raw, ivr stored). Selection
// is block-uniform (no divergence). Saves one launch gap and overlaps the
// two packs' memory phases.
// Fragment layout (verified by R23 passing): frag f = comp*2 + kfrag; lane l
// holds token (l&15), k = kfrag*32 + (l>>4)*8 + e. A and B use IDENTICAL
// packing -> within-lane k-order deviations cancel in the dot product.
// ---------------------------------------------------------------------------
__global__ __launch_bounds__(TPB) void k_pack(const float* __restrict__ x,
                                              const int* __restrict__ cntK,
                                              const int* __restrict__ listK,
                                              float4* __restrict__ colA,
                                              const int* __restrict__ cntP,
                                              const int* __restrict__ listP,
                                              float4* __restrict__ rowB,
                                              float* __restrict__ ivrArr) {
    int id = blockIdx.x;
    const bool isA = id < BB * MAXT;
    if (!isA) id -= BB * MAXT;
    const int b = id & 15;
    const int t = id >> 4;                  // 0..MAXT-1
    const int C = isA ? cntK[b] : cntP[b];
    const int* __restrict__ list = isA ? listK : listP;
    float4* __restrict__ outF = isA ? colA : rowB;

    const int lane = threadIdx.x & 63;
    const int wid  = threadIdx.x >> 6;
    __shared__ float4 stage4[384];          // 6 KB fragment tile
    unsigned short* st = (unsigned short*)stage4;
    const float* xb = x + (size_t)b * NN * CC;

    const int g  = (lane >> 3) & 3;         // k-group within 32-frag
    const int kf = lane >> 5;               // k-frag 0/1
    const int e  = lane & 7;                // element within 8
#pragma unroll
    for (int it = 0; it < 4; ++it) {
        int ci = wid * 4 + it;              // token within tile 0..15
        int cp = t * 16 + ci;               // compacted position
        float v = 0.0f;
        if (cp < C) {
            int tok = list[b * NN + cp];
            float xv = xb[(size_t)tok * CC + lane];
            float sq = xv * xv;
#pragma unroll
            for (int off = 32; off; off >>= 1) sq += __shfl_xor(sq, off, 64);
            float ivr = 1.0f / (sqrtf(sq) + 1e-6f);
            if (!isA && lane == 0) ivrArr[b * IVN + cp] = ivr;
            v = isA ? xv * ivr : xv;
        }
        unsigned short hb = rnbf16(v);
        float r1 = v - bf2f(hb);
        unsigned short mb = rnbf16(r1);
        float r2 = r1 - bf2f(mb);
        unsigned short lb = rnbf16(r2);
        int lt = ci + g * 16;               // target fragment lane
        st[((0 + kf) * 64 + lt) * 8 + e] = hb;   // comp h -> frags 0,1
        st[((2 + kf) * 64 + lt) * 8 + e] = mb;   // comp m -> frags 2,3
        st[((4 + kf) * 64 + lt) * 8 + e] = lb;   // comp l -> frags 4,5
    }
    __syncthreads();
    float4* dst = outF + (size_t)(b * MAXT + t) * 384;
    for (int i = threadIdx.x; i < 384; i += TPB) dst[i] = stage4[i];
}

// ---------------------------------------------------------------------------
// K3: MFMA GEMM-argmax (R24: 32 ROWS PER BLOCK, A-tile register reuse).
// R23 budget back-solve: k_argmax ~30us vs floors {colA L2 stream 393MB ~11us,
// MFMA issue ~1.6us} -> latency-exposed per-tile load->wait->MFMA (hipcc does
// not pipeline VMEM across iterations) at ~4 live waves/SIMD.
// This round: each block holds TWO row-tiles' B-frags resident (12 bf16x8 =
// 48 VGPR) and reuses every loaded A-tile for 24 MFMAs (was 12):
//  - colA traffic HALVES (1024->512 live-block sweeps; ~200MB, ~6us floor);
//  - compute window per 6-load round doubles (120->240 issue cy) -> covers
//    most of the ~300cy L2 latency even at 2 live blocks/CU;
//  - 4 independent acc chains (S0/H0/S1/H1) keep the MFMA pipe fed.
// Term set + per-(row,col) MFMA order BYTE-IDENTICAL to R23 (verified pass):
// same tie fidelity. Emission = R23's disjoint-col ballot walk, done per
// row-half (wave-uniform branch selects tmax/msk set).
// Grid 1024 (1024%16==0: XCD pin kept); early-exit blocks harmless (R6/R7).
// Counter check: VGPR <= 64 => allocator re-materialized B-frags (R3 mode,
// test void). Expect VGPR 110-145.
// ---------------------------------------------------------------------------
__global__ __launch_bounds__(TPB) void k_argmax(
    const float* __restrict__ x,
    const float4* __restrict__ colA,   // [BB][MAXT] 6KB fragment tiles
    const float4* __restrict__ rowB,   // [BB][MAXT] 6KB fragment tiles
    const float* __restrict__ ivrArr,  // [BB][IVN] 1/(||row||+eps)
    const int* __restrict__ cntP, const int* __restrict__ cntK,
    const int* __restrict__ listP, const int* __restrict__ listK,
    float* __restrict__ S,             // [B,N] zeroed by k_pre
    float* __restrict__ A) {           // [B,N,C] zeroed by k_pre; = d_out

    const int b  = blockIdx.x & 15;
    const int rt = blockIdx.x >> 4;    // 32-row slot, 0..63
    const int P = cntP[b], K = cntK[b];
    const int base = rt * 32;
    if (base >= P) return;

    const int lane = threadIdx.x & 63;
    const int wid  = threadIdx.x >> 6;

    // B fragments for both row-tiles: resident for the whole sweep (48 VGPR)
    const float4* rb0 = rowB + (size_t)(b * MAXT + 2 * rt) * 384;
    const float4* rb1 = rb0 + 384;
    bf16x8 B0h0 = __builtin_bit_cast(bf16x8, rb0[0 * 64 + lane]);
    bf16x8 B1h0 = __builtin_bit_cast(bf16x8, rb0[1 * 64 + lane]);
    bf16x8 B0m0 = __builtin_bit_cast(bf16x8, rb0[2 * 64 + lane]);
    bf16x8 B1m0 = __builtin_bit_cast(bf16x8, rb0[3 * 64 + lane]);
    bf16x8 B0l0 = __builtin_bit_cast(bf16x8, rb0[4 * 64 + lane]);
    bf16x8 B1l0 = __builtin_bit_cast(bf16x8, rb0[5 * 64 + lane]);
    bf16x8 B0h1 = __builtin_bit_cast(bf16x8, rb1[0 * 64 + lane]);
    bf16x8 B1h1 = __builtin_bit_cast(bf16x8, rb1[1 * 64 + lane]);
    bf16x8 B0m1 = __builtin_bit_cast(bf16x8, rb1[2 * 64 + lane]);
    bf16x8 B1m1 = __builtin_bit_cast(bf16x8, rb1[3 * 64 + lane]);
    bf16x8 B0l1 = __builtin_bit_cast(bf16x8, rb1[4 * 64 + lane]);
    bf16x8 B1l1 = __builtin_bit_cast(bf16x8, rb1[5 * 64 + lane]);

    float tmax0 = -3.0e38f, tmax1 = -3.0e38f;
    unsigned long long mA0 = 0ull, mB0 = 0ull, mA1 = 0ull, mB1 = 0ull;
    const int NT = (K + 15) >> 4;
    const float4* ca = colA + (size_t)b * MAXT * 384;
    const int cgrp = (lane >> 4) << 2;

    int i = 0;
    for (int t = wid; t < NT; t += 4, ++i) {
        const float4* af = ca + (size_t)t * 384;
        bf16x8 A0h = __builtin_bit_cast(bf16x8, af[0 * 64 + lane]);
        bf16x8 A1h = __builtin_bit_cast(bf16x8, af[1 * 64 + lane]);
        bf16x8 A0m = __builtin_bit_cast(bf16x8, af[2 * 64 + lane]);
        bf16x8 A1m = __builtin_bit_cast(bf16x8, af[3 * 64 + lane]);
        bf16x8 A0l = __builtin_bit_cast(bf16x8, af[4 * 64 + lane]);
        bf16x8 A1l = __builtin_bit_cast(bf16x8, af[5 * 64 + lane]);

        // 24 MFMA / tile-pass: 4 independent chains (order per (row,col)
        // identical to R23: S = mm,hl,lh ; H = hm,mh,hh ; s = H+S).
        f32x4 accS0 = {0.f,0.f,0.f,0.f}, accH0 = {0.f,0.f,0.f,0.f};
        f32x4 accS1 = {0.f,0.f,0.f,0.f}, accH1 = {0.f,0.f,0.f,0.f};
        accS0 = MFMA(A0m, B0m0, accS0); accS0 = MFMA(A1m, B1m0, accS0);
        accS1 = MFMA(A0m, B0m1, accS1); accS1 = MFMA(A1m, B1m1, accS1);
        accS0 = MFMA(A0h, B0l0, accS0); accS0 = MFMA(A1h, B1l0, accS0);
        accS1 = MFMA(A0h, B0l1, accS1); accS1 = MFMA(A1h, B1l1, accS1);
        accS0 = MFMA(A0l, B0h0, accS0); accS0 = MFMA(A1l, B1h0, accS0);
        accS1 = MFMA(A0l, B0h1, accS1); accS1 = MFMA(A1l, B1h1, accS1);
        accH0 = MFMA(A0h, B0m0, accH0); accH0 = MFMA(A1h, B1m0, accH0);
        accH1 = MFMA(A0h, B0m1, accH1); accH1 = MFMA(A1h, B1m1, accH1);
        accH0 = MFMA(A0m, B0h0, accH0); accH0 = MFMA(A1m, B1h0, accH0);
        accH1 = MFMA(A0m, B0h1, accH1); accH1 = MFMA(A1m, B1h1, accH1);
        accH0 = MFMA(A0h, B0h0, accH0); accH0 = MFMA(A1h, B1h0, accH0);
        accH1 = MFMA(A0h, B0h1, accH1); accH1 = MFMA(A1h, B1h1, accH1);

        const int cb = t * 16 + cgrp;
        const int ib = (i & 15) << 2;
#pragma unroll
        for (int j = 0; j < 4; ++j) {
            float s0 = accH0[j] + accS0[j];
            float s1 = accH1[j] + accS1[j];
            bool ok = (cb + j < K);
            s0 = ok ? s0 : -3.0e38f;
            s1 = ok ? s1 : -3.0e38f;
            unsigned long long bit = 1ull << (ib | j);
            if (i < 16) {                        // wave-uniform branch
                if (s0 > tmax0)       { tmax0 = s0; mA0 = bit; mB0 = 0ull; }
                else if (s0 == tmax0)  mA0 |= bit;
                if (s1 > tmax1)       { tmax1 = s1; mA1 = bit; mB1 = 0ull; }
                else if (s1 == tmax1)  mA1 |= bit;
            } else {
                if (s0 > tmax0)       { tmax0 = s0; mB0 = bit; mA0 = 0ull; }
                else if (s0 == tmax0)  mB0 |= bit;
                if (s1 > tmax1)       { tmax1 = s1; mB1 = bit; mA1 = 0ull; }
                else if (s1 == tmax1)  mB1 |= bit;
            }
            // pad note (R23-verified): junk ties on pad cols only exist while
            // tmax == -3e38; every lane's first tile has real cols, so junk
            // is overwritten before emission can see it.
        }
    }

    // ---- merge per-row maxima: lanes r,r+16,r+32,r+48 in-wave, then LDS ----
    float m0 = tmax0, m1 = tmax1;
    m0 = fmaxf(m0, __shfl_xor(m0, 16, 64)); m0 = fmaxf(m0, __shfl_xor(m0, 32, 64));
    m1 = fmaxf(m1, __shfl_xor(m1, 16, 64)); m1 = fmaxf(m1, __shfl_xor(m1, 32, 64));
    __shared__ float mW[32][4];
    if (lane < 16) { mW[lane][wid] = m0; mW[16 + lane][wid] = m1; }
    __syncthreads();

    // ---- emission: each wave walks its own disjoint col subset ----
    const int nvr = min(32, P - base);
    for (int r = 0; r < nvr; ++r) {
        const int half = r >> 4;              // wave-uniform
        float M = fmaxf(fmaxf(mW[r][0], mW[r][1]), fmaxf(mW[r][2], mW[r][3]));
        float myT = half ? tmax1 : tmax0;
        unsigned long long bal = __ballot((lane & 15) == (r & 15) && myT == M);
        if (bal == 0ull) continue;            // no winners in this wave
        int src = listP[b * NN + base + r];
        float ivr = ivrArr[b * IVN + base + r];
        float wgt = expf(M * ivr);
        float xv = x[((size_t)b * NN + src) * CC + lane];
        while (bal) {
            int sl = __ffsll(bal) - 1;
            bal &= bal - 1;
            unsigned long long mAs = __shfl(half ? mA1 : mA0, sl);
            unsigned long long mBs = __shfl(half ? mB1 : mB0, sl);
            int cg = (sl >> 4) << 2;
            while (mAs) {
                int bb = __ffsll(mAs) - 1; mAs &= mAs - 1;
                int colp = (wid + 4 * (bb >> 2)) * 16 + cg + (bb & 3);
                int dst = listK[b * NN + colp];
                atomicAdd(&A[((size_t)b * NN + dst) * CC + lane], wgt * xv);
                if (lane == 0) atomicAdd(&S[b * NN + dst], wgt);
            }
            while (mBs) {
                int bb = __ffsll(mBs) - 1; mBs &= mBs - 1;
                int colp = (wid + 4 * (16 + (bb >> 2))) * 16 + cg + (bb & 3);
                int dst = listK[b * NN + colp];
                atomicAdd(&A[((size_t)b * NN + dst) * CC + lane], wgt * xv);
                if (lane == 0) atomicAdd(&S[b * NN + dst], wgt);
            }
        }
    }
}

// ---------------------------------------------------------------------------
// K4: out = (e*x + A) / (e + S).  A aliases d_out (in-place), float4.
// ---------------------------------------------------------------------------
__global__ __launch_bounds__(TPB) void k_finalize(const float* __restrict__ x,
                                                  const float* __restrict__ S,
                                                  float* __restrict__ out) {
    int i = blockIdx.x * TPB + threadIdx.x;
    int row = i >> 4;
    float inv = 1.0f / (E_CONST + S[row]);
    float4 xv = ((const float4*)x)[i];
    float4 av = ((float4*)out)[i];
    float4 o;
    o.x = (xv.x * E_CONST + av.x) * inv;
    o.y = (xv.y * E_CONST + av.y) * inv;
    o.z = (xv.z * E_CONST + av.z) * inv;
    o.w = (xv.w * E_CONST + av.w) * inv;
    ((float4*)out)[i] = o;
}

// ---------------------------------------------------------------------------
extern "C" void kernel_launch(void* const* d_in, const int* in_sizes, int n_in,
                              void* d_out, int out_size, void* d_ws, size_t ws_size,
                              hipStream_t stream) {
    const float* x    = (const float*)d_in[0];
    const float* keep = (const float*)d_in[2];
    float* out = (float*)d_out;

    // ws: reserved 128K | S 128K | cnts 128B | listP 128K | listK 128K |
    //     ivr 74K @768K | colA 6.75MB @1M | rowB 6.75MB @8M  (~14.8MB total)
    char* ws = (char*)d_ws;
    float* S     = (float*)(ws + (128 << 10));
    int*   cntP  = (int*)(ws + (256 << 10));
    int*   cntK  = cntP + 16;
    int*   listP = (int*)(ws + (256 << 10) + 128);
    int*   listK = listP + BB * NN;
    float* ivrArr = (float*)(ws + (768 << 10));
    float4* colA = (float4*)(ws + (1 << 20));
    float4* rowB = (float4*)(ws + (8 << 20));

    k_pre<<<512, TPB, 0, stream>>>(keep, out, S, cntP, cntK, listP, listK);

    // single pack launch: [0,1152) -> colA (normalized), [1152,2304) -> rowB+ivr
    k_pack<<<2 * BB * MAXT, TPB, 0, stream>>>(x, cntK, listK, colA,
                                              cntP, listP, rowB, ivrArr);

    // 1-D grid: b = id & 15 (XCD pinning), 32-row slot = id >> 4.
    k_argmax<<<1024, TPB, 0, stream>>>(x, colA, rowB, ivrArr,
                                       cntP, cntK, listP, listK, S, out);

    k_finalize<<<(BB * NN * CC / 4) / TPB, TPB, 0, stream>>>(x, S, out);
}

// Round 10
// 122.842 us; speedup vs baseline: 1.0052x; 1.0052x over previous
//
#include <hip/hip_runtime.h>
#include <math.h>

// Problem constants (B,N,C fixed by the reference setup).
#define BB 16
#define NN 2048
#define CC 64
#define TPB 256
#define MAXT 72           // 16-token tiles per batch per side; K,P <= 1152 (+5.6 sigma)
#define IVN (MAXT * 16)
#define E_CONST 2.71828182845904523536f

typedef __attribute__((ext_vector_type(8))) short bf16x8;   // 8 bf16 = 4 VGPR
typedef __attribute__((ext_vector_type(4))) float f32x4;
#define MFMA(A_, B_, C_) __builtin_amdgcn_mfma_f32_16x16x32_bf16(A_, B_, C_, 0, 0, 0)

// round-to-nearest-even f32 -> bf16 bits
__device__ __forceinline__ unsigned short rnbf16(float v) {
    unsigned u = __float_as_uint(v);
    return (unsigned short)((u + 0x7FFFu + ((u >> 16) & 1u)) >> 16);
}
__device__ __forceinline__ float bf2f(unsigned short h) {
    return __uint_as_float((unsigned)h << 16);
}

// ---------------------------------------------------------------------------
// K_pre: zero the A accumulator (d_out) everywhere; blocks 0..BB-1 also run
// ballot-based kept/pruned compaction for batch b and zero S[b,:].
// ---------------------------------------------------------------------------
__global__ __launch_bounds__(TPB) void k_pre(const float* __restrict__ keep,
                                             float* __restrict__ outz,
                                             float* __restrict__ S,
                                             int* __restrict__ cntP,
                                             int* __restrict__ cntK,
                                             int* __restrict__ listP,
                                             int* __restrict__ listK) {
    const int tid = threadIdx.x, lane = tid & 63;

    float4* o4 = (float4*)outz + (size_t)blockIdx.x * 1024;
    float4 z = {0.0f, 0.0f, 0.0f, 0.0f};
#pragma unroll
    for (int i = 0; i < 4; ++i) o4[i * TPB + tid] = z;

    const int b = blockIdx.x;
    if (b >= BB) return;

    __shared__ int cP, cK;
    if (tid == 0) { cP = 0; cK = 0; }
    __syncthreads();
    for (int i = tid; i < NN; i += TPB) S[b * NN + i] = 0.0f;
    const unsigned long long lt = (lane == 63) ? 0x7fffffffffffffffull
                                               : ((1ull << lane) - 1ull);
#pragma unroll
    for (int it = 0; it < NN / TPB; ++it) {
        int n = it * TPB + tid;
        bool kp = keep[b * NN + n] != 0.0f;
        unsigned long long mk = __ballot(kp);
        int nk = __popcll(mk);
        int bk = 0, bp = 0;
        if (lane == 0) {
            bk = atomicAdd(&cK, nk);
            bp = atomicAdd(&cP, 64 - nk);
        }
        bk = __shfl(bk, 0); bp = __shfl(bp, 0);
        int pk = __popcll(mk & lt);
        if (kp) listK[b * NN + bk + pk] = n;
        else    listP[b * NN + bp + (lane - pk)] = n;
    }
    __syncthreads();
    if (tid == 0) { cntP[b] = cP; cntK[b] = cK; }
}

// ---------------------------------------------------------------------------
// K_pack (R24-verified, unchanged): both operands in ONE launch.
// Blocks [0, BB*MAXT) build colA (normalized); [BB*MAXT, 2*BB*MAXT) build
// rowB (raw, ivr stored). Block-uniform selection, no divergence.
// Fragment layout (R23/R24-verified): frag f = comp*2 + kfrag; lane l holds
// token (l&15), k = kfrag*32 + (l>>4)*8 + e. A and B use IDENTICAL packing
// -> within-lane k-order deviations cancel in the dot product.
// ---------------------------------------------------------------------------
__global__ __launch_bounds__(TPB) void k_pack(const float* __restrict__ x,
                                              const int* __restrict__ cntK,
                                              const int* __restrict__ listK,
                                              float4* __restrict__ colA,
                                              const int* __restrict__ cntP,
                                              const int* __restrict__ listP,
                                              float4* __restrict__ rowB,
                                              float* __restrict__ ivrArr) {
    int id = blockIdx.x;
    const bool isA = id < BB * MAXT;
    if (!isA) id -= BB * MAXT;
    const int b = id & 15;
    const int t = id >> 4;                  // 0..MAXT-1
    const int C = isA ? cntK[b] : cntP[b];
    const int* __restrict__ list = isA ? listK : listP;
    float4* __restrict__ outF = isA ? colA : rowB;

    const int lane = threadIdx.x & 63;
    const int wid  = threadIdx.x >> 6;
    __shared__ float4 stage4[384];          // 6 KB fragment tile
    unsigned short* st = (unsigned short*)stage4;
    const float* xb = x + (size_t)b * NN * CC;

    const int g  = (lane >> 3) & 3;         // k-group within 32-frag
    const int kf = lane >> 5;               // k-frag 0/1
    const int e  = lane & 7;                // element within 8
#pragma unroll
    for (int it = 0; it < 4; ++it) {
        int ci = wid * 4 + it;              // token within tile 0..15
        int cp = t * 16 + ci;               // compacted position
        float v = 0.0f;
        if (cp < C) {
            int tok = list[b * NN + cp];
            float xv = xb[(size_t)tok * CC + lane];
            float sq = xv * xv;
#pragma unroll
            for (int off = 32; off; off >>= 1) sq += __shfl_xor(sq, off, 64);
            float ivr = 1.0f / (sqrtf(sq) + 1e-6f);
            if (!isA && lane == 0) ivrArr[b * IVN + cp] = ivr;
            v = isA ? xv * ivr : xv;
        }
        unsigned short hb = rnbf16(v);
        float r1 = v - bf2f(hb);
        unsigned short mb = rnbf16(r1);
        float r2 = r1 - bf2f(mb);
        unsigned short lb = rnbf16(r2);
        int lt = ci + g * 16;               // target fragment lane
        st[((0 + kf) * 64 + lt) * 8 + e] = hb;   // comp h -> frags 0,1
        st[((2 + kf) * 64 + lt) * 8 + e] = mb;   // comp m -> frags 2,3
        st[((4 + kf) * 64 + lt) * 8 + e] = lb;   // comp l -> frags 4,5
    }
    __syncthreads();
    float4* dst = outF + (size_t)(b * MAXT + t) * 384;
    for (int i = threadIdx.x; i < 384; i += TPB) dst[i] = stage4[i];
}

// ---------------------------------------------------------------------------
// K3: MFMA GEMM-argmax (R25 = R23 champion + 2-DEEP A-TILE PREFETCH).
// R9 post-mortem: 32-row reuse regressed (live blocks halved -> less latency
// hiding); k_argmax's ~30us is ~90% exposed L2 latency (issue floors: MFMA
// 1.6us, VALU 2us, L2-BW 11us) because hipcc emits load->waitcnt->MFMA per
// tile with no cross-iteration pipeline at 4 waves/SIMD.
// Fix: alternating Aa/Ab register sets (STATIC names, rule #20); each wave
// issues tile k+1's 6 loads BEFORE computing tile k, so ~150cy of compute
// overlaps the ~250cy L2 latency. R5's version of this failed at 2 blocks/CU
// + VGPR 164; here the grid keeps 4 blocks/CU and the budget (~100-120 VGPR)
// must stay <= 128 (4 waves/SIMD) -- VGPR > 128 voids the test.
// Compute/emission/mask semantics BYTE-IDENTICAL to the R23/R24-verified
// kernel (same 6-term order, same pad guard, same disjoint-col ballot walk).
// ---------------------------------------------------------------------------
__device__ __forceinline__ void loadA6(const float4* __restrict__ af, int lane,
                                       bf16x8& h0, bf16x8& h1, bf16x8& m0,
                                       bf16x8& m1, bf16x8& l0, bf16x8& l1) {
    h0 = __builtin_bit_cast(bf16x8, af[0 * 64 + lane]);
    h1 = __builtin_bit_cast(bf16x8, af[1 * 64 + lane]);
    m0 = __builtin_bit_cast(bf16x8, af[2 * 64 + lane]);
    m1 = __builtin_bit_cast(bf16x8, af[3 * 64 + lane]);
    l0 = __builtin_bit_cast(bf16x8, af[4 * 64 + lane]);
    l1 = __builtin_bit_cast(bf16x8, af[5 * 64 + lane]);
}

__device__ __forceinline__ void computeTile(
    bf16x8 A0h, bf16x8 A1h, bf16x8 A0m, bf16x8 A1m, bf16x8 A0l, bf16x8 A1l,
    bf16x8 B0h, bf16x8 B1h, bf16x8 B0m, bf16x8 B1m, bf16x8 B0l, bf16x8 B1l,
    int t, int i, int K, int cgrp,
    float& tmax, unsigned long long& mskA, unsigned long long& mskB) {
    // two independent accumulation chains (order identical to R23)
    f32x4 accS = {0.f, 0.f, 0.f, 0.f}, accH = {0.f, 0.f, 0.f, 0.f};
    accS = MFMA(A0m, B0m, accS); accS = MFMA(A1m, B1m, accS);   // mm
    accS = MFMA(A0h, B0l, accS); accS = MFMA(A1h, B1l, accS);   // hl
    accS = MFMA(A0l, B0h, accS); accS = MFMA(A1l, B1h, accS);   // lh
    accH = MFMA(A0h, B0m, accH); accH = MFMA(A1h, B1m, accH);   // hm
    accH = MFMA(A0m, B0h, accH); accH = MFMA(A1m, B1h, accH);   // mh
    accH = MFMA(A0h, B0h, accH); accH = MFMA(A1h, B1h, accH);   // hh

    const int cb = t * 16 + cgrp;
    const int ib = (i & 15) << 2;
#pragma unroll
    for (int j = 0; j < 4; ++j) {
        float s = accH[j] + accS[j];
        s = (cb + j < K) ? s : -3.0e38f;     // pad guard (R23 note applies)
        unsigned long long bit = 1ull << (ib | j);
        if (i < 16) {                        // wave-uniform branch
            if (s > tmax)       { tmax = s; mskA = bit; mskB = 0ull; }
            else if (s == tmax)  mskA |= bit;
        } else {
            if (s > tmax)       { tmax = s; mskB = bit; mskA = 0ull; }
            else if (s == tmax)  mskB |= bit;
        }
    }
}

__global__ __launch_bounds__(TPB) void k_argmax(
    const float* __restrict__ x,
    const float4* __restrict__ colA,   // [BB][MAXT] 6KB fragment tiles
    const float4* __restrict__ rowB,   // [BB][MAXT] 6KB fragment tiles
    const float* __restrict__ ivrArr,  // [BB][IVN] 1/(||row||+eps)
    const int* __restrict__ cntP, const int* __restrict__ cntK,
    const int* __restrict__ listP, const int* __restrict__ listK,
    float* __restrict__ S,             // [B,N] zeroed by k_pre
    float* __restrict__ A) {           // [B,N,C] zeroed by k_pre; = d_out

    const int b  = blockIdx.x & 15;
    const int rt = blockIdx.x >> 4;
    const int P = cntP[b], K = cntK[b];
    const int base = rt * 16;
    if (base >= P) return;

    const int lane = threadIdx.x & 63;
    const int wid  = threadIdx.x >> 6;

    // row fragments: resident for the whole sweep (24 VGPR)
    const float4* rb = rowB + (size_t)(b * MAXT + rt) * 384;
    bf16x8 B0h, B1h, B0m, B1m, B0l, B1l;
    loadA6(rb, lane, B0h, B1h, B0m, B1m, B0l, B1l);

    float tmax = -3.0e38f;
    unsigned long long mskA = 0ull, mskB = 0ull;
    const int NT = (K + 15) >> 4;
    const float4* ca = colA + (size_t)b * MAXT * 384;
    const int cgrp = (lane >> 4) << 2;

    // Software pipeline, depth 2: alternating Aa/Ab register sets.
    const int ntw = (NT - wid + 3) >> 2;   // tiles for this wave (wid < NT always)
    bf16x8 Aa0h, Aa1h, Aa0m, Aa1m, Aa0l, Aa1l;
    bf16x8 Ab0h, Ab1h, Ab0m, Ab1m, Ab0l, Ab1l;

    if (ntw > 0)
        loadA6(ca + (size_t)wid * 384, lane, Aa0h, Aa1h, Aa0m, Aa1m, Aa0l, Aa1l);
    int k = 0;
    while (k < ntw) {
        if (k + 1 < ntw)                    // issue k+1 BEFORE computing k
            loadA6(ca + (size_t)(wid + 4 * (k + 1)) * 384, lane,
                   Ab0h, Ab1h, Ab0m, Ab1m, Ab0l, Ab1l);
        computeTile(Aa0h, Aa1h, Aa0m, Aa1m, Aa0l, Aa1l,
                    B0h, B1h, B0m, B1m, B0l, B1l,
                    wid + 4 * k, k, K, cgrp, tmax, mskA, mskB);
        ++k;
        if (k >= ntw) break;
        if (k + 1 < ntw)
            loadA6(ca + (size_t)(wid + 4 * (k + 1)) * 384, lane,
                   Aa0h, Aa1h, Aa0m, Aa1m, Aa0l, Aa1l);
        computeTile(Ab0h, Ab1h, Ab0m, Ab1m, Ab0l, Ab1l,
                    B0h, B1h, B0m, B1m, B0l, B1l,
                    wid + 4 * k, k, K, cgrp, tmax, mskA, mskB);
        ++k;
    }

    // ---- merge per-row maxima: lanes r,r+16,r+32,r+48 in-wave, then LDS ----
    float m = tmax;
    m = fmaxf(m, __shfl_xor(m, 16, 64));
    m = fmaxf(m, __shfl_xor(m, 32, 64));
    __shared__ float mW[16][4];
    if (lane < 16) mW[lane][wid] = m;
    __syncthreads();

    // ---- emission: each wave walks its own disjoint col subset ----
    const int nvr = min(16, P - base);
    for (int r = 0; r < nvr; ++r) {
        float M = fmaxf(fmaxf(mW[r][0], mW[r][1]), fmaxf(mW[r][2], mW[r][3]));
        unsigned long long bal = __ballot((lane & 15) == r && tmax == M);
        if (bal == 0ull) continue;              // no winners in this wave
        int src = listP[b * NN + base + r];
        float ivr = ivrArr[b * IVN + base + r];
        float wgt = expf(M * ivr);
        float xv = x[((size_t)b * NN + src) * CC + lane];
        while (bal) {
            int sl = __ffsll(bal) - 1;
            bal &= bal - 1;
            unsigned long long mA = __shfl(mskA, sl);
            unsigned long long mB = __shfl(mskB, sl);
            int cg = (sl >> 4) << 2;
            while (mA) {
                int bb = __ffsll(mA) - 1; mA &= mA - 1;
                int colp = (wid + 4 * (bb >> 2)) * 16 + cg + (bb & 3);
                int dst = listK[b * NN + colp];
                atomicAdd(&A[((size_t)b * NN + dst) * CC + lane], wgt * xv);
                if (lane == 0) atomicAdd(&S[b * NN + dst], wgt);
            }
            while (mB) {
                int bb = __ffsll(mB) - 1; mB &= mB - 1;
                int colp = (wid + 4 * (16 + (bb >> 2))) * 16 + cg + (bb & 3);
                int dst = listK[b * NN + colp];
                atomicAdd(&A[((size_t)b * NN + dst) * CC + lane], wgt * xv);
                if (lane == 0) atomicAdd(&S[b * NN + dst], wgt);
            }
        }
    }
}

// ---------------------------------------------------------------------------
// K4: out = (e*x + A) / (e + S).  A aliases d_out (in-place), float4.
// ---------------------------------------------------------------------------
__global__ __launch_bounds__(TPB) void k_finalize(const float* __restrict__ x,
                                                  const float* __restrict__ S,
                                                  float* __restrict__ out) {
    int i = blockIdx.x * TPB + threadIdx.x;
    int row = i >> 4;
    float inv = 1.0f / (E_CONST + S[row]);
    float4 xv = ((const float4*)x)[i];
    float4 av = ((float4*)out)[i];
    float4 o;
    o.x = (xv.x * E_CONST + av.x) * inv;
    o.y = (xv.y * E_CONST + av.y) * inv;
    o.z = (xv.z * E_CONST + av.z) * inv;
    o.w = (xv.w * E_CONST + av.w) * inv;
    ((float4*)out)[i] = o;
}

// ---------------------------------------------------------------------------
extern "C" void kernel_launch(void* const* d_in, const int* in_sizes, int n_in,
                              void* d_out, int out_size, void* d_ws, size_t ws_size,
                              hipStream_t stream) {
    const float* x    = (const float*)d_in[0];
    const float* keep = (const float*)d_in[2];
    float* out = (float*)d_out;

    // ws: reserved 128K | S 128K | cnts 128B | listP 128K | listK 128K |
    //     ivr 74K @768K | colA 6.75MB @1M | rowB 6.75MB @8M  (~14.8MB total)
    char* ws = (char*)d_ws;
    float* S     = (float*)(ws + (128 << 10));
    int*   cntP  = (int*)(ws + (256 << 10));
    int*   cntK  = cntP + 16;
    int*   listP = (int*)(ws + (256 << 10) + 128);
    int*   listK = listP + BB * NN;
    float* ivrArr = (float*)(ws + (768 << 10));
    float4* colA = (float4*)(ws + (1 << 20));
    float4* rowB = (float4*)(ws + (8 << 20));

    k_pre<<<512, TPB, 0, stream>>>(keep, out, S, cntP, cntK, listP, listK);

    // single pack launch: [0,1152) -> colA (normalized), [1152,2304) -> rowB+ivr
    k_pack<<<2 * BB * MAXT, TPB, 0, stream>>>(x, cntK, listK, colA,
                                              cntP, listP, rowB, ivrArr);

    // 1-D grid: b = id & 15 (XCD pinning), 16-row slot = id >> 4.
    k_argmax<<<2048, TPB, 0, stream>>>(x, colA, rowB, ivrArr,
                                       cntP, cntK, listP, listK, S, out);

    k_finalize<<<(BB * NN * CC / 4) / TPB, TPB, 0, stream>>>(x, S, out);
}

// Round 11
// 120.741 us; speedup vs baseline: 1.0227x; 1.0174x over previous
//
#include <hip/hip_runtime.h>
#include <math.h>

// Problem constants (B,N,C fixed by the reference setup).
#define BB 16
#define NN 2048
#define CC 64
#define TPB 256
#define TPA 512           // k_argmax block: 8 waves = 4 col-streams x 2 row-halves
#define MAXT 72           // 16-token tiles per batch per side; K,P <= 1152 (+5.6 sigma)
#define IVN (MAXT * 16)
#define E_CONST 2.71828182845904523536f

typedef __attribute__((ext_vector_type(8))) short bf16x8;   // 8 bf16 = 4 VGPR
typedef __attribute__((ext_vector_type(4))) float f32x4;
#define MFMA(A_, B_, C_) __builtin_amdgcn_mfma_f32_16x16x32_bf16(A_, B_, C_, 0, 0, 0)

// round-to-nearest-even f32 -> bf16 bits
__device__ __forceinline__ unsigned short rnbf16(float v) {
    unsigned u = __float_as_uint(v);
    return (unsigned short)((u + 0x7FFFu + ((u >> 16) & 1u)) >> 16);
}
__device__ __forceinline__ float bf2f(unsigned short h) {
    return __uint_as_float((unsigned)h << 16);
}

// ---------------------------------------------------------------------------
// K_pre: zero the A accumulator (d_out) everywhere; blocks 0..BB-1 also run
// ballot-based kept/pruned compaction for batch b and zero S[b,:].
// ---------------------------------------------------------------------------
__global__ __launch_bounds__(TPB) void k_pre(const float* __restrict__ keep,
                                             float* __restrict__ outz,
                                             float* __restrict__ S,
                                             int* __restrict__ cntP,
                                             int* __restrict__ cntK,
                                             int* __restrict__ listP,
                                             int* __restrict__ listK) {
    const int tid = threadIdx.x, lane = tid & 63;

    float4* o4 = (float4*)outz + (size_t)blockIdx.x * 1024;
    float4 z = {0.0f, 0.0f, 0.0f, 0.0f};
#pragma unroll
    for (int i = 0; i < 4; ++i) o4[i * TPB + tid] = z;

    const int b = blockIdx.x;
    if (b >= BB) return;

    __shared__ int cP, cK;
    if (tid == 0) { cP = 0; cK = 0; }
    __syncthreads();
    for (int i = tid; i < NN; i += TPB) S[b * NN + i] = 0.0f;
    const unsigned long long lt = (lane == 63) ? 0x7fffffffffffffffull
                                               : ((1ull << lane) - 1ull);
#pragma unroll
    for (int it = 0; it < NN / TPB; ++it) {
        int n = it * TPB + tid;
        bool kp = keep[b * NN + n] != 0.0f;
        unsigned long long mk = __ballot(kp);
        int nk = __popcll(mk);
        int bk = 0, bp = 0;
        if (lane == 0) {
            bk = atomicAdd(&cK, nk);
            bp = atomicAdd(&cP, 64 - nk);
        }
        bk = __shfl(bk, 0); bp = __shfl(bp, 0);
        int pk = __popcll(mk & lt);
        if (kp) listK[b * NN + bk + pk] = n;
        else    listP[b * NN + bp + (lane - pk)] = n;
    }
    __syncthreads();
    if (tid == 0) { cntP[b] = cP; cntK[b] = cK; }
}

// ---------------------------------------------------------------------------
// K_pack (R24-verified, unchanged): both operands in ONE launch.
// Blocks [0, BB*MAXT) build colA (normalized); [BB*MAXT, 2*BB*MAXT) build
// rowB (raw, ivr stored). Block-uniform selection, no divergence.
// Fragment layout (R23/R24-verified): frag f = comp*2 + kfrag; lane l holds
// token (l&15), k = kfrag*32 + (l>>4)*8 + e. A and B use IDENTICAL packing
// -> within-lane k-order deviations cancel in the dot product.
// ---------------------------------------------------------------------------
__global__ __launch_bounds__(TPB) void k_pack(const float* __restrict__ x,
                                              const int* __restrict__ cntK,
                                              const int* __restrict__ listK,
                                              float4* __restrict__ colA,
                                              const int* __restrict__ cntP,
                                              const int* __restrict__ listP,
                                              float4* __restrict__ rowB,
                                              float* __restrict__ ivrArr) {
    int id = blockIdx.x;
    const bool isA = id < BB * MAXT;
    if (!isA) id -= BB * MAXT;
    const int b = id & 15;
    const int t = id >> 4;                  // 0..MAXT-1
    const int C = isA ? cntK[b] : cntP[b];
    const int* __restrict__ list = isA ? listK : listP;
    float4* __restrict__ outF = isA ? colA : rowB;

    const int lane = threadIdx.x & 63;
    const int wid  = threadIdx.x >> 6;
    __shared__ float4 stage4[384];          // 6 KB fragment tile
    unsigned short* st = (unsigned short*)stage4;
    const float* xb = x + (size_t)b * NN * CC;

    const int g  = (lane >> 3) & 3;         // k-group within 32-frag
    const int kf = lane >> 5;               // k-frag 0/1
    const int e  = lane & 7;                // element within 8
#pragma unroll
    for (int it = 0; it < 4; ++it) {
        int ci = wid * 4 + it;              // token within tile 0..15
        int cp = t * 16 + ci;               // compacted position
        float v = 0.0f;
        if (cp < C) {
            int tok = list[b * NN + cp];
            float xv = xb[(size_t)tok * CC + lane];
            float sq = xv * xv;
#pragma unroll
            for (int off = 32; off; off >>= 1) sq += __shfl_xor(sq, off, 64);
            float ivr = 1.0f / (sqrtf(sq) + 1e-6f);
            if (!isA && lane == 0) ivrArr[b * IVN + cp] = ivr;
            v = isA ? xv * ivr : xv;
        }
        unsigned short hb = rnbf16(v);
        float r1 = v - bf2f(hb);
        unsigned short mb = rnbf16(r1);
        float r2 = r1 - bf2f(mb);
        unsigned short lb = rnbf16(r2);
        int lt = ci + g * 16;               // target fragment lane
        st[((0 + kf) * 64 + lt) * 8 + e] = hb;   // comp h -> frags 0,1
        st[((2 + kf) * 64 + lt) * 8 + e] = mb;   // comp m -> frags 2,3
        st[((4 + kf) * 64 + lt) * 8 + e] = lb;   // comp l -> frags 4,5
    }
    __syncthreads();
    float4* dst = outF + (size_t)(b * MAXT + t) * 384;
    for (int i = threadIdx.x; i < 384; i += TPB) dst[i] = stage4[i];
}

// ---------------------------------------------------------------------------
// K3: MFMA GEMM-argmax (R26: 32 rows/block, 8 waves, PAIRED-WAVE L1 REUSE).
// R8/R9/R10 matrix: {traffic halved + occupancy halved} = -3us; {scheduling
// only} = 0; untested cell = {traffic halved + occupancy CONSTANT}:
//  - block = 32 rows (2 row-tiles) x 8 waves; wave w: col-stream cs = w>>1,
//    row-half h = w&1. Per-wave shape IDENTICAL to R8 (16 rows in 24 B-VGPR,
//    12-MFMA pass, same term order -> identical numerics & tie fidelity).
//  - wave-pairs (2k,2k+1) read the SAME A-tile stream for the two halves:
//    second read hits per-CU L1 -> L2 traffic halves (393->197MB, floor
//    11.4->5.7us) at CONSTANT 16 waves/CU (2 blocks x 8 vs R8's 4 x 4).
//  - R10's prefetch reverted (measured neutral); plain R8 loop body.
//  - emission: R8's disjoint-col ballot walk per row-half; merge table
//    mW[32][4] (cs column), 512B LDS, 1 barrier; wave-uniform half gating.
// Grid 1024 (b = id&15 XCD pin; 1024%16==0); dead blocks harmless (R6/R7).
// VGPR must stay <=128 for 4 waves/SIMD (else void, R3 mode).
// ---------------------------------------------------------------------------
__device__ __forceinline__ void loadF6(const float4* __restrict__ af, int lane,
                                       bf16x8& h0, bf16x8& h1, bf16x8& m0,
                                       bf16x8& m1, bf16x8& l0, bf16x8& l1) {
    h0 = __builtin_bit_cast(bf16x8, af[0 * 64 + lane]);
    h1 = __builtin_bit_cast(bf16x8, af[1 * 64 + lane]);
    m0 = __builtin_bit_cast(bf16x8, af[2 * 64 + lane]);
    m1 = __builtin_bit_cast(bf16x8, af[3 * 64 + lane]);
    l0 = __builtin_bit_cast(bf16x8, af[4 * 64 + lane]);
    l1 = __builtin_bit_cast(bf16x8, af[5 * 64 + lane]);
}

__global__ __launch_bounds__(TPA) void k_argmax(
    const float* __restrict__ x,
    const float4* __restrict__ colA,   // [BB][MAXT] 6KB fragment tiles
    const float4* __restrict__ rowB,   // [BB][MAXT] 6KB fragment tiles
    const float* __restrict__ ivrArr,  // [BB][IVN] 1/(||row||+eps)
    const int* __restrict__ cntP, const int* __restrict__ cntK,
    const int* __restrict__ listP, const int* __restrict__ listK,
    float* __restrict__ S,             // [B,N] zeroed by k_pre
    float* __restrict__ A) {           // [B,N,C] zeroed by k_pre; = d_out

    const int b  = blockIdx.x & 15;
    const int rt = blockIdx.x >> 4;    // 32-row slot, 0..63
    const int P = cntP[b], K = cntK[b];
    const int base = rt * 32;
    if (base >= P) return;             // block-uniform

    const int tid  = threadIdx.x;
    const int lane = tid & 63;
    const int wid  = tid >> 6;         // 0..7
    const int cs   = wid >> 1;         // col-stream 0..3
    const int h    = wid & 1;          // row-half 0/1

    // this wave's row-tile fragments (2*rt+h < 72 whenever base < P <= 1152)
    const float4* rb = rowB + (size_t)(b * MAXT + 2 * rt + h) * 384;
    bf16x8 B0h, B1h, B0m, B1m, B0l, B1l;
    loadF6(rb, lane, B0h, B1h, B0m, B1m, B0l, B1l);

    float tmax = -3.0e38f;
    unsigned long long mskA = 0ull, mskB = 0ull;
    const int NT = (K + 15) >> 4;
    const float4* ca = colA + (size_t)b * MAXT * 384;
    const int cgrp = (lane >> 4) << 2;

    int i = 0;
    for (int t = cs; t < NT; t += 4, ++i) {
        const float4* af = ca + (size_t)t * 384;
        bf16x8 A0h, A1h, A0m, A1m, A0l, A1l;
        loadF6(af, lane, A0h, A1h, A0m, A1m, A0l, A1l);

        // two independent accumulation chains (order identical to R23/R24)
        f32x4 accS = {0.f, 0.f, 0.f, 0.f}, accH = {0.f, 0.f, 0.f, 0.f};
        accS = MFMA(A0m, B0m, accS); accS = MFMA(A1m, B1m, accS);   // mm
        accS = MFMA(A0h, B0l, accS); accS = MFMA(A1h, B1l, accS);   // hl
        accS = MFMA(A0l, B0h, accS); accS = MFMA(A1l, B1h, accS);   // lh
        accH = MFMA(A0h, B0m, accH); accH = MFMA(A1h, B1m, accH);   // hm
        accH = MFMA(A0m, B0h, accH); accH = MFMA(A1m, B1h, accH);   // mh
        accH = MFMA(A0h, B0h, accH); accH = MFMA(A1h, B1h, accH);   // hh

        const int cb = t * 16 + cgrp;
        const int ib = (i & 15) << 2;
#pragma unroll
        for (int j = 0; j < 4; ++j) {
            float s = accH[j] + accS[j];
            s = (cb + j < K) ? s : -3.0e38f;     // pad guard (R23 note)
            unsigned long long bit = 1ull << (ib | j);
            if (i < 16) {                        // wave-uniform branch
                if (s > tmax)       { tmax = s; mskA = bit; mskB = 0ull; }
                else if (s == tmax)  mskA |= bit;
            } else {
                if (s > tmax)       { tmax = s; mskB = bit; mskA = 0ull; }
                else if (s == tmax)  mskB |= bit;
            }
        }
    }

    // ---- merge per-row maxima: in-wave (lanes r,r+16,r+32,r+48), then LDS --
    float m = tmax;
    m = fmaxf(m, __shfl_xor(m, 16, 64));
    m = fmaxf(m, __shfl_xor(m, 32, 64));
    __shared__ float mW[32][4];
    if (lane < 16) mW[h * 16 + lane][cs] = m;
    __syncthreads();

    // ---- emission: waves of half (r>>4) walk their disjoint col subsets ----
    const int nvr = min(32, P - base);
    for (int r = 0; r < nvr; ++r) {
        if ((r >> 4) != h) continue;            // wave-uniform half gate
        float M = fmaxf(fmaxf(mW[r][0], mW[r][1]), fmaxf(mW[r][2], mW[r][3]));
        unsigned long long bal = __ballot((lane & 15) == (r & 15) && tmax == M);
        if (bal == 0ull) continue;              // no winners in this wave
        int src = listP[b * NN + base + r];
        float ivr = ivrArr[b * IVN + base + r];
        float wgt = expf(M * ivr);
        float xv = x[((size_t)b * NN + src) * CC + lane];
        while (bal) {
            int sl = __ffsll(bal) - 1;
            bal &= bal - 1;
            unsigned long long mA = __shfl(mskA, sl);
            unsigned long long mB = __shfl(mskB, sl);
            int cg = (sl >> 4) << 2;
            while (mA) {
                int bb = __ffsll(mA) - 1; mA &= mA - 1;
                int colp = (cs + 4 * (bb >> 2)) * 16 + cg + (bb & 3);
                int dst = listK[b * NN + colp];
                atomicAdd(&A[((size_t)b * NN + dst) * CC + lane], wgt * xv);
                if (lane == 0) atomicAdd(&S[b * NN + dst], wgt);
            }
            while (mB) {
                int bb = __ffsll(mB) - 1; mB &= mB - 1;
                int colp = (cs + 4 * (16 + (bb >> 2))) * 16 + cg + (bb & 3);
                int dst = listK[b * NN + colp];
                atomicAdd(&A[((size_t)b * NN + dst) * CC + lane], wgt * xv);
                if (lane == 0) atomicAdd(&S[b * NN + dst], wgt);
            }
        }
    }
}

// ---------------------------------------------------------------------------
// K4: out = (e*x + A) / (e + S).  A aliases d_out (in-place), float4.
// ---------------------------------------------------------------------------
__global__ __launch_bounds__(TPB) void k_finalize(const float* __restrict__ x,
                                                  const float* __restrict__ S,
                                                  float* __restrict__ out) {
    int i = blockIdx.x * TPB + threadIdx.x;
    int row = i >> 4;
    float inv = 1.0f / (E_CONST + S[row]);
    float4 xv = ((const float4*)x)[i];
    float4 av = ((float4*)out)[i];
    float4 o;
    o.x = (xv.x * E_CONST + av.x) * inv;
    o.y = (xv.y * E_CONST + av.y) * inv;
    o.z = (xv.z * E_CONST + av.z) * inv;
    o.w = (xv.w * E_CONST + av.w) * inv;
    ((float4*)out)[i] = o;
}

// ---------------------------------------------------------------------------
extern "C" void kernel_launch(void* const* d_in, const int* in_sizes, int n_in,
                              void* d_out, int out_size, void* d_ws, size_t ws_size,
                              hipStream_t stream) {
    const float* x    = (const float*)d_in[0];
    const float* keep = (const float*)d_in[2];
    float* out = (float*)d_out;

    // ws: reserved 128K | S 128K | cnts 128B | listP 128K | listK 128K |
    //     ivr 74K @768K | colA 6.75MB @1M | rowB 6.75MB @8M  (~14.8MB total)
    char* ws = (char*)d_ws;
    float* S     = (float*)(ws + (128 << 10));
    int*   cntP  = (int*)(ws + (256 << 10));
    int*   cntK  = cntP + 16;
    int*   listP = (int*)(ws + (256 << 10) + 128);
    int*   listK = listP + BB * NN;
    float* ivrArr = (float*)(ws + (768 << 10));
    float4* colA = (float4*)(ws + (1 << 20));
    float4* rowB = (float4*)(ws + (8 << 20));

    k_pre<<<512, TPB, 0, stream>>>(keep, out, S, cntP, cntK, listP, listK);

    // single pack launch: [0,1152) -> colA (normalized), [1152,2304) -> rowB+ivr
    k_pack<<<2 * BB * MAXT, TPB, 0, stream>>>(x, cntK, listK, colA,
                                              cntP, listP, rowB, ivrArr);

    // 1-D grid: b = id & 15 (XCD pinning), 32-row slot = id >> 4; 8 waves.
    k_argmax<<<1024, TPA, 0, stream>>>(x, colA, rowB, ivrArr,
                                       cntP, cntK, listP, listK, S, out);

    k_finalize<<<(BB * NN * CC / 4) / TPB, TPB, 0, stream>>>(x, S, out);
}